// Round 9
// baseline (220.482 us; speedup 1.0000x reference)
//
#include <hip/hip_runtime.h>
#include <hip/hip_bf16.h>
#include <float.h>

#define BB 2
#define NN 256
#define DD 64
#define KK 16
#define NH 4
#define HID 128
#define KVD 256
#define RH 64
#define NNODES (BB*NN)      // 512
#define NEDGES (NNODES*KK)  // 8192

typedef unsigned int uint32;
typedef unsigned short ushort_t;
typedef float f32x4_t __attribute__((ext_vector_type(4)));
typedef short bf16x8_t __attribute__((ext_vector_type(8)));

__device__ __forceinline__ uint32 cvtpk_bf16(float lo, float hi) {
  uint32 r;
  asm("v_cvt_pk_bf16_f32 %0, %1, %2" : "=v"(r) : "v"(lo), "v"(hi));
  return r;
}

__device__ __forceinline__ float wave_sum64(float v) {
  #pragma unroll
  for (int m = 32; m; m >>= 1) v += __shfl_xor(v, m, 64);
  return v;
}
__device__ __forceinline__ float grp32_sum(float v) {
  #pragma unroll
  for (int m = 16; m; m >>= 1) v += __shfl_xor(v, m, 64);
  return v;
}

// ---------------- Kernel 1: [blocks 0..127] prenorm + q/xi/xj (4 nodes/block)
//                  [blocks 128..647] W3(+b3) fp32 -> bf16 convert --------------
__global__ __launch_bounds__(256) void node_w3_kernel(
    const float* __restrict__ feat, const float* __restrict__ gscale,
    const float* __restrict__ Wq, const float* __restrict__ Wxi,
    const float* __restrict__ Wxj,
    const float* __restrict__ W3, const float* __restrict__ b3,
    float* __restrict__ q_ws, float* __restrict__ xi_ws, float* __restrict__ xj_ws,
    ushort_t* __restrict__ W3bf) {
  int bx = blockIdx.x;
  if (bx >= 128) {
    // ---- w3cvt part: layout [65][256*64], row 64 = b3
    const int W3N = 64 * KVD * DD;               // 1,048,576
    int i = ((bx - 128) * 256 + threadIdx.x) * 8;  // total 65*16384
    const float* src = (i < W3N) ? (W3 + i) : (b3 + (i - W3N));
    float4 a = ((const float4*)src)[0];
    float4 b = ((const float4*)src)[1];
    float v[8] = {a.x, a.y, a.z, a.w, b.x, b.y, b.z, b.w};
    union { uint4 q; ushort_t s[8]; } o;
    #pragma unroll
    for (int jj = 0; jj < 8; ++jj) {
      uint32 u = __float_as_uint(v[jj]);
      o.s[jj] = (ushort_t)((u + 0x7FFFu + ((u >> 16) & 1u)) >> 16);  // RNE
    }
    *(uint4*)(W3bf + i) = o.q;
    return;
  }
  // ---- node part: 4 nodes per block, one wave each
  int sub = threadIdx.x >> 6;
  int t = threadIdx.x & 63;
  int node = bx * 4 + sub;
  __shared__ float xs[4][DD];
  float f = feat[node * DD + t];
  float ss = wave_sum64(f * f);
  float rms = sqrtf(ss) * 0.125f;           // * d^-0.5 (d=64)
  float den = fmaxf(rms, 1e-12f);
  float x = f / den * gscale[t];
  xs[sub][t] = x;
  __syncthreads();
  float q0 = 0.f, q1 = 0.f, xiv = 0.f, xjv = 0.f;
  #pragma unroll 4
  for (int d = 0; d < DD; ++d) {
    float xv = xs[sub][d];
    q0  += xv * Wq[d * HID + t];
    q1  += xv * Wq[d * HID + 64 + t];
    xiv += xv * Wxi[d * DD + t];
    xjv += xv * Wxj[d * DD + t];
  }
  q_ws[node * HID + t] = q0;
  q_ws[node * HID + 64 + t] = q1;
  xi_ws[node * DD + t] = xiv;
  xj_ws[node * DD + t] = xjv;
}

// ---------------- Kernel 2: radial MLP (2 LN layers) + xe gather (one block per edge)
__global__ __launch_bounds__(64) void edge_kernel(
    const int* __restrict__ nbi, const float* __restrict__ rel,
    const float* __restrict__ W1, const float* __restrict__ b1,
    const float* __restrict__ g1, const float* __restrict__ W2,
    const float* __restrict__ b2, const float* __restrict__ g2,
    const float* __restrict__ xi_ws, const float* __restrict__ xj_ws,
    float* __restrict__ h2_ws, float* __restrict__ xe_ws) {
  int e = blockIdx.x;
  int t = threadIdx.x;
  int node = e >> 4;
  int j = e & 15;
  int bb = node >> 8;
  __shared__ float hs[RH];
  float rd = rel[e];
  float h = rd * W1[t] + b1[t];
  h = h / (1.f + expf(-h));                          // silu
  float mu = wave_sum64(h) * (1.f / RH);
  float c = h - mu;
  float var = wave_sum64(c * c) * (1.f / RH);
  float xn = c * rsqrtf(var + 1e-5f) * g1[t];
  hs[t] = xn;
  __syncthreads();
  float p = b2[t];
  #pragma unroll 4
  for (int r = 0; r < RH; ++r) p += hs[r] * W2[r * RH + t];
  p = p / (1.f + expf(-p));
  mu = wave_sum64(p) * (1.f / RH);
  c = p - mu;
  var = wave_sum64(c * c) * (1.f / RH);
  float h2v = c * rsqrtf(var + 1e-5f) * g2[t];
  h2_ws[e * RH + t] = h2v;
  int nb = nbi[node * KK + j];
  xe_ws[e * DD + t] = xj_ws[(bb * NN + nb) * DD + t] + xi_ws[node * DD + t];
}

// ---------------- Kernel 3: kv via bf16 MFMA, M=32/wave, K-split x2 in-block ------
// kv[e,o] = sum_{r<=64} h2'[e,r] * sum_d xe[e,d]*W3bf[r][o*64+d]   (h2'[*,64]=1 bias)
// Block: 256 thr = 4 waves. wv = w | rh<<1: w = edge half (32 edges), rh = r half.
// rh=0: r 0..31; rh=1: r 32..63 + bias row 64. Partials merged via LDS (h2_s reuse).
#define LOADB(dst, rr) {                                          \
  const ushort_t* s_ = Wp + (size_t)(rr) * (KVD * DD);            \
  dst[0] = *(const bf16x8_t*)(s_);                                \
  dst[1] = *(const bf16x8_t*)(s_ + 32);                           \
  dst[2] = *(const bf16x8_t*)(s_ + 1024);                         \
  dst[3] = *(const bf16x8_t*)(s_ + 1056);                         \
  dst[4] = *(const bf16x8_t*)(s_ + 2048);                         \
  dst[5] = *(const bf16x8_t*)(s_ + 2080);                         \
  dst[6] = *(const bf16x8_t*)(s_ + 3072);                         \
  dst[7] = *(const bf16x8_t*)(s_ + 3104); }

#define AFRAG(dst, arr, base, h) {                                \
  union { bf16x8_t v; uint32 u[4]; } t_;                          \
  t_.u[0] = cvtpk_bf16(arr[(base)+0]*(h), arr[(base)+1]*(h));     \
  t_.u[1] = cvtpk_bf16(arr[(base)+2]*(h), arr[(base)+3]*(h));     \
  t_.u[2] = cvtpk_bf16(arr[(base)+4]*(h), arr[(base)+5]*(h));     \
  t_.u[3] = cvtpk_bf16(arr[(base)+6]*(h), arr[(base)+7]*(h));     \
  dst = t_.v; }

#define STEPH(hA_, hB_, bb) {                                     \
  bf16x8_t a0A, a1A, a0B, a1B;                                    \
  AFRAG(a0A, xfA, 0, hA_); AFRAG(a1A, xfA, 8, hA_);               \
  AFRAG(a0B, xfB, 0, hB_); AFRAG(a1B, xfB, 8, hB_);               \
  accA0 = __builtin_amdgcn_mfma_f32_16x16x32_bf16(a0A, bb[0], accA0, 0, 0, 0); \
  accA0 = __builtin_amdgcn_mfma_f32_16x16x32_bf16(a1A, bb[1], accA0, 0, 0, 0); \
  accA1 = __builtin_amdgcn_mfma_f32_16x16x32_bf16(a0A, bb[2], accA1, 0, 0, 0); \
  accA1 = __builtin_amdgcn_mfma_f32_16x16x32_bf16(a1A, bb[3], accA1, 0, 0, 0); \
  accA2 = __builtin_amdgcn_mfma_f32_16x16x32_bf16(a0A, bb[4], accA2, 0, 0, 0); \
  accA2 = __builtin_amdgcn_mfma_f32_16x16x32_bf16(a1A, bb[5], accA2, 0, 0, 0); \
  accA3 = __builtin_amdgcn_mfma_f32_16x16x32_bf16(a0A, bb[6], accA3, 0, 0, 0); \
  accA3 = __builtin_amdgcn_mfma_f32_16x16x32_bf16(a1A, bb[7], accA3, 0, 0, 0); \
  accB0 = __builtin_amdgcn_mfma_f32_16x16x32_bf16(a0B, bb[0], accB0, 0, 0, 0); \
  accB0 = __builtin_amdgcn_mfma_f32_16x16x32_bf16(a1B, bb[1], accB0, 0, 0, 0); \
  accB1 = __builtin_amdgcn_mfma_f32_16x16x32_bf16(a0B, bb[2], accB1, 0, 0, 0); \
  accB1 = __builtin_amdgcn_mfma_f32_16x16x32_bf16(a1B, bb[3], accB1, 0, 0, 0); \
  accB2 = __builtin_amdgcn_mfma_f32_16x16x32_bf16(a0B, bb[4], accB2, 0, 0, 0); \
  accB2 = __builtin_amdgcn_mfma_f32_16x16x32_bf16(a1B, bb[5], accB2, 0, 0, 0); \
  accB3 = __builtin_amdgcn_mfma_f32_16x16x32_bf16(a0B, bb[6], accB3, 0, 0, 0); \
  accB3 = __builtin_amdgcn_mfma_f32_16x16x32_bf16(a1B, bb[7], accB3, 0, 0, 0); }

__global__ __launch_bounds__(256) void kv_kernel(
    const ushort_t* __restrict__ W3bf,
    const float* __restrict__ h2_ws, const float* __restrict__ xe_ws,
    float* __restrict__ kv_ws) {
  int bx = blockIdx.x;
  int eb = bx >> 2, ob = bx & 3;       // 128 edge-groups x 4 col-groups
  int o0 = ob * 64;
  int tid = threadIdx.x;
  int wv = tid >> 6;
  int w = wv & 1, rh = wv >> 1;        // edge-half, r-half
  int l = tid & 63;
  int l15 = l & 15, g = l >> 4;        // g in 0..3
  int ebase = eb * 64;
  __shared__ float h2_s[64 * 68];      // h2 tile; reused for partial-acc exchange
  {  // stage h2 tile [64 edges][64 r] -> LDS stride 68 (256 thr, 16 floats each)
    int row = tid >> 2, c0 = (tid & 3) * 16;
    const float* src = h2_ws + (ebase + row) * RH + c0;
    float* dst = &h2_s[row * 68 + c0];
    #pragma unroll
    for (int q = 0; q < 4; ++q) ((float4*)dst)[q] = ((const float4*)src)[q];
  }
  // xe fragments (fp32) direct from global: two edge rows per lane
  int erowA = ebase + w * 32 + l15;
  const float* xsrcA = xe_ws + erowA * DD + g * 8;
  const float* xsrcB = xsrcA + 16 * DD;
  float xfA[16], xfB[16];
  #pragma unroll
  for (int jj = 0; jj < 8; ++jj) { xfA[jj] = xsrcA[jj]; xfA[8 + jj] = xsrcA[32 + jj]; }
  #pragma unroll
  for (int jj = 0; jj < 8; ++jj) { xfB[jj] = xsrcB[jj]; xfB[8 + jj] = xsrcB[32 + jj]; }
  __syncthreads();

  int eA68 = (w * 32 + l15) * 68;
  int eB68 = eA68 + 16 * 68;
  const ushort_t* Wp = W3bf + (size_t)(o0 + l15) * 64 + g * 8;
  f32x4_t accA0 = {0,0,0,0}, accA1 = {0,0,0,0}, accA2 = {0,0,0,0}, accA3 = {0,0,0,0};
  f32x4_t accB0 = {0,0,0,0}, accB1 = {0,0,0,0}, accB2 = {0,0,0,0}, accB3 = {0,0,0,0};
  bf16x8_t buf[4][8];
  float hA[4], hB[4];
  int rbeg = rh * 32;
  #pragma unroll
  for (int u = 0; u < 4; ++u) {
    LOADB(buf[u], rbeg + u);
    hA[u] = h2_s[eA68 + rbeg + u];
    hB[u] = h2_s[eB68 + rbeg + u];
  }
  for (int r = rbeg; r < rbeg + 32; r += 4) {
    #pragma unroll
    for (int u = 0; u < 4; ++u) {
      STEPH(hA[u], hB[u], buf[u]);
      int rn = r + 4 + u;
      int rc = (rn > 64) ? 64 : rn;       // row 64 = bias row (rh=1 tail)
      LOADB(buf[u], rc);
      int hn = (rn > 67) ? 67 : rn;       // cols 64..67 = pad (values unused)
      hA[u] = h2_s[eA68 + hn];
      hB[u] = h2_s[eB68 + hn];
    }
  }
  if (rh) STEPH(1.0f, 1.0f, buf[0]);      // bias step r=64 (buf[0] holds row 64)
  __syncthreads();                        // all h2_s reads done
  // D layout (m89-verified): col = lane&15, row = (lane>>4)*4 + reg
  if (rh) {  // upper-r waves deposit partials into LDS [64][68]
    #pragma unroll
    for (int q = 0; q < 4; ++q) {
      int ra = (w * 32 + g * 4 + q) * 68 + l15;
      int rb = ra + 16 * 68;
      h2_s[ra +  0] = accA0[q];
      h2_s[ra + 16] = accA1[q];
      h2_s[ra + 32] = accA2[q];
      h2_s[ra + 48] = accA3[q];
      h2_s[rb +  0] = accB0[q];
      h2_s[rb + 16] = accB1[q];
      h2_s[rb + 32] = accB2[q];
      h2_s[rb + 48] = accB3[q];
    }
  }
  __syncthreads();
  if (!rh) {  // lower-r waves add partials and write
    int orowA = (ebase + w * 32 + g * 4) * KVD + o0 + l15;
    int orowB = orowA + 16 * KVD;
    #pragma unroll
    for (int q = 0; q < 4; ++q) {
      int ra = (w * 32 + g * 4 + q) * 68 + l15;
      int rb = ra + 16 * 68;
      kv_ws[orowA + q * KVD +  0] = accA0[q] + h2_s[ra +  0];
      kv_ws[orowA + q * KVD + 16] = accA1[q] + h2_s[ra + 16];
      kv_ws[orowA + q * KVD + 32] = accA2[q] + h2_s[ra + 32];
      kv_ws[orowA + q * KVD + 48] = accA3[q] + h2_s[ra + 48];
      kv_ws[orowB + q * KVD +  0] = accB0[q] + h2_s[rb +  0];
      kv_ws[orowB + q * KVD + 16] = accB1[q] + h2_s[rb + 16];
      kv_ws[orowB + q * KVD + 32] = accB2[q] + h2_s[rb + 32];
      kv_ws[orowB + q * KVD + 48] = accB3[q] + h2_s[rb + 48];
    }
  }
}

// ---------------- Kernel 4: fused (kv @ Wkv_out) + L2-dist attention + out-proj ---
__global__ __launch_bounds__(128) void attn_kernel(
    const float* __restrict__ q_ws, const float* __restrict__ kv_ws,
    const int* __restrict__ maskp, const float* __restrict__ Wkv,
    const float* __restrict__ Wout, float* __restrict__ out) {
  int node = blockIdx.x;
  int t = threadIdx.x;             // 128 = H*dh
  int h = t >> 5;
  __shared__ float kvs[KK * 260];  // 16 edges x 256 (pad 260 vs write conflicts)
  __shared__ float sim_s[NH * KK];
  __shared__ float o_s[HID];
  {  // stage kv[16][256]
    int e = t >> 3, c0 = (t & 7) * 32;
    const float* src = kv_ws + (node * KK + e) * KVD + c0;
    float* dst = &kvs[e * 260 + c0];
    #pragma unroll
    for (int q = 0; q < 8; ++q) ((float4*)dst)[q] = ((const float4*)src)[q];
  }
  __syncthreads();
  // kv2 in-block: kk2[e] = sum_k kvs[e][k]*Wkv[k][t]; vv2[e] = ...Wkv[k][128+t]
  float kk2[KK] = {}, vv2[KK] = {};
  #pragma unroll 4
  for (int k = 0; k < KVD; ++k) {
    float w1 = Wkv[k * KVD + t];
    float w2 = Wkv[k * KVD + 128 + t];
    #pragma unroll
    for (int e = 0; e < KK; ++e) {
      float kvv = kvs[e * 260 + k];   // wave-uniform address -> broadcast
      kk2[e] += kvv * w1;
      vv2[e] += kvv * w2;
    }
  }
  float qv = q_ws[node * HID + t];
  const float scale = 0.17677669529663689f;   // 32^-0.5
  #pragma unroll
  for (int j = 0; j < KK; ++j) {
    float diff = qv - kk2[j] + 1e-6f;
    float s = grp32_sum(diff * diff);
    if ((t & 31) == 0) sim_s[h * KK + j] = -sqrtf(s) * scale;
  }
  __syncthreads();
  float sv[KK];
  float m = -FLT_MAX;
  #pragma unroll
  for (int j = 0; j < KK; ++j) {
    bool msk = maskp[node * KK + j] != 0;
    float s = msk ? sim_s[h * KK + j] : -FLT_MAX;
    sv[j] = s;
    m = fmaxf(m, s);
  }
  float sum = 0.f, wv[KK];
  #pragma unroll
  for (int j = 0; j < KK; ++j) { wv[j] = expf(sv[j] - m); sum += wv[j]; }
  float inv = 1.f / sum;
  float ot = 0.f;
  #pragma unroll
  for (int j = 0; j < KK; ++j) ot += wv[j] * vv2[j];
  o_s[t] = ot * inv;
  __syncthreads();
  if (t < DD) {
    float r = 0.f;
    #pragma unroll 4
    for (int cI = 0; cI < HID; ++cI) r += o_s[cI] * Wout[cI * DD + t];
    out[node * DD + t] = r;
  }
}

extern "C" void kernel_launch(void* const* d_in, const int* in_sizes, int n_in,
                              void* d_out, int out_size, void* d_ws, size_t ws_size,
                              hipStream_t stream) {
  const float* feat = (const float*)d_in[0];
  const int*   nbi  = (const int*)d_in[1];
  const int*   msk  = (const int*)d_in[2];
  const float* rel  = (const float*)d_in[3];
  const float* gsc  = (const float*)d_in[4];
  const float* Wq   = (const float*)d_in[5];
  const float* Wxi  = (const float*)d_in[6];
  const float* Wxj  = (const float*)d_in[7];
  const float* W1   = (const float*)d_in[8];
  const float* b1   = (const float*)d_in[9];
  const float* g1   = (const float*)d_in[10];
  const float* W2   = (const float*)d_in[11];
  const float* b2   = (const float*)d_in[12];
  const float* g2   = (const float*)d_in[13];
  const float* W3   = (const float*)d_in[14];
  const float* b3   = (const float*)d_in[15];
  const float* Wkv  = (const float*)d_in[16];
  const float* Wout = (const float*)d_in[17];

  float* ws      = (float*)d_ws;
  float* q_ws    = ws;                          // 512*128
  float* xi_ws   = q_ws  + NNODES * HID;        // 512*64
  float* xj_ws   = xi_ws + NNODES * DD;         // 512*64
  float* h2_ws   = xj_ws + NNODES * DD;         // 8192*64
  float* xe_ws   = h2_ws + NEDGES * RH;         // 8192*64
  float* kv_ws   = xe_ws + NEDGES * DD;         // 8192*256
  ushort_t* W3bf = (ushort_t*)(kv_ws + NEDGES * KVD);   // 65*16384 bf16 (~2.1 MB)

  node_w3_kernel<<<648, 256, 0, stream>>>(feat, gsc, Wq, Wxi, Wxj, W3, b3,
                                          q_ws, xi_ws, xj_ws, W3bf);
  edge_kernel<<<NEDGES, 64, 0, stream>>>(nbi, rel, W1, b1, g1, W2, b2, g2,
                                         xi_ws, xj_ws, h2_ws, xe_ws);
  kv_kernel<<<512, 256, 0, stream>>>(W3bf, h2_ws, xe_ws, kv_ws);
  attn_kernel<<<NNODES, 128, 0, stream>>>(q_ws, kv_ws, msk, Wkv, Wout,
                                          (float*)d_out);
}

// Round 10
// 185.794 us; speedup vs baseline: 1.1867x; 1.1867x over previous
//
#include <hip/hip_runtime.h>
#include <hip/hip_bf16.h>
#include <float.h>

#define BB 2
#define NN 256
#define DD 64
#define KK 16
#define NH 4
#define HID 128
#define KVD 256
#define RH 64
#define NNODES (BB*NN)      // 512
#define NEDGES (NNODES*KK)  // 8192

typedef unsigned int uint32;
typedef unsigned short ushort_t;
typedef float f32x4_t __attribute__((ext_vector_type(4)));
typedef short bf16x8_t __attribute__((ext_vector_type(8)));
typedef __attribute__((address_space(3))) ushort_t lds_us;
typedef __attribute__((address_space(1))) const ushort_t glb_us;

__device__ __forceinline__ uint32 cvtpk_bf16(float lo, float hi) {
  uint32 r;
  asm("v_cvt_pk_bf16_f32 %0, %1, %2" : "=v"(r) : "v"(lo), "v"(hi));
  return r;
}

__device__ __forceinline__ float wave_sum64(float v) {
  #pragma unroll
  for (int m = 32; m; m >>= 1) v += __shfl_xor(v, m, 64);
  return v;
}
__device__ __forceinline__ float grp32_sum(float v) {
  #pragma unroll
  for (int m = 16; m; m >>= 1) v += __shfl_xor(v, m, 64);
  return v;
}

// ---------------- Kernel 1: [blocks 0..127] prenorm + q/xi/xj (4 nodes/block)
//                  [blocks 128..647] W3(+b3) fp32 -> bf16, SWIZZLED layout ---------
// W3bf layout: row r (65 rows: 64 W3-rows + b3), within row: element (o,d) at byte
//   o*128 + ((gr*16) ^ ((o&7)<<4)),  gr = d/8   (XOR kills ds_read bank conflicts)
__global__ __launch_bounds__(256) void node_w3_kernel(
    const float* __restrict__ feat, const float* __restrict__ gscale,
    const float* __restrict__ Wq, const float* __restrict__ Wxi,
    const float* __restrict__ Wxj,
    const float* __restrict__ W3, const float* __restrict__ b3,
    float* __restrict__ q_ws, float* __restrict__ xi_ws, float* __restrict__ xj_ws,
    ushort_t* __restrict__ W3bf) {
  int bx = blockIdx.x;
  if (bx >= 128) {
    const int W3N = 64 * KVD * DD;               // 1,048,576
    int i = ((bx - 128) * 256 + threadIdx.x) * 8;  // 8 elems per thread
    const float* src = (i < W3N) ? (W3 + i) : (b3 + (i - W3N));
    float4 a = ((const float4*)src)[0];
    float4 b = ((const float4*)src)[1];
    float v[8] = {a.x, a.y, a.z, a.w, b.x, b.y, b.z, b.w};
    union { uint4 q; ushort_t s[8]; } o;
    #pragma unroll
    for (int jj = 0; jj < 8; ++jj) {
      uint32 u = __float_as_uint(v[jj]);
      o.s[jj] = (ushort_t)((u + 0x7FFFu + ((u >> 16) & 1u)) >> 16);  // RNE
    }
    int rr = i >> 14, j0 = i & 16383;
    int oc = j0 >> 6, gr = (j0 >> 3) & 7;
    int byte_sw = oc * 128 + ((gr * 16) ^ ((oc & 7) << 4));
    *(uint4*)(W3bf + (rr << 14) + (byte_sw >> 1)) = o.q;
    return;
  }
  int sub = threadIdx.x >> 6;
  int t = threadIdx.x & 63;
  int node = bx * 4 + sub;
  __shared__ float xs[4][DD];
  float f = feat[node * DD + t];
  float ss = wave_sum64(f * f);
  float rms = sqrtf(ss) * 0.125f;
  float den = fmaxf(rms, 1e-12f);
  float x = f / den * gscale[t];
  xs[sub][t] = x;
  __syncthreads();
  float q0 = 0.f, q1 = 0.f, xiv = 0.f, xjv = 0.f;
  #pragma unroll 4
  for (int d = 0; d < DD; ++d) {
    float xv = xs[sub][d];
    q0  += xv * Wq[d * HID + t];
    q1  += xv * Wq[d * HID + 64 + t];
    xiv += xv * Wxi[d * DD + t];
    xjv += xv * Wxj[d * DD + t];
  }
  q_ws[node * HID + t] = q0;
  q_ws[node * HID + 64 + t] = q1;
  xi_ws[node * DD + t] = xiv;
  xj_ws[node * DD + t] = xjv;
}

// ---------------- Kernel 2: radial MLP (2 LN layers) + xe gather (one block per edge)
__global__ __launch_bounds__(64) void edge_kernel(
    const int* __restrict__ nbi, const float* __restrict__ rel,
    const float* __restrict__ W1, const float* __restrict__ b1,
    const float* __restrict__ g1, const float* __restrict__ W2,
    const float* __restrict__ b2, const float* __restrict__ g2,
    const float* __restrict__ xi_ws, const float* __restrict__ xj_ws,
    float* __restrict__ h2_ws, float* __restrict__ xe_ws) {
  int e = blockIdx.x;
  int t = threadIdx.x;
  int node = e >> 4;
  int j = e & 15;
  int bb = node >> 8;
  __shared__ float hs[RH];
  float rd = rel[e];
  float h = rd * W1[t] + b1[t];
  h = h / (1.f + expf(-h));                          // silu
  float mu = wave_sum64(h) * (1.f / RH);
  float c = h - mu;
  float var = wave_sum64(c * c) * (1.f / RH);
  float xn = c * rsqrtf(var + 1e-5f) * g1[t];
  hs[t] = xn;
  __syncthreads();
  float p = b2[t];
  #pragma unroll 4
  for (int r = 0; r < RH; ++r) p += hs[r] * W2[r * RH + t];
  p = p / (1.f + expf(-p));
  mu = wave_sum64(p) * (1.f / RH);
  c = p - mu;
  var = wave_sum64(c * c) * (1.f / RH);
  float h2v = c * rsqrtf(var + 1e-5f) * g2[t];
  h2_ws[e * RH + t] = h2v;
  int nb = nbi[node * KK + j];
  xe_ws[e * DD + t] = xj_ws[(bb * NN + nb) * DD + t] + xi_ws[node * DD + t];
}

// ---------------- Kernel 3: kv via bf16 MFMA, LDS-staged B (global_load_lds) ------
// kv[e,o] = sum_{r<=64} h2'[e,r] * sum_d xe[e,d]*W3bf[r][o*64+d]   (h2'[*,64]=1 bias)
// Block: 256 thr = 4 waves, 64 edges x 64 o.  Wave we: edges [ebase+we*16, +16).
// B: 2 rows/phase (16KB) double-buffered in LDS via global_load_lds; 33 phases.
#define AFRAG(dst, base, h) {                                     \
  union { bf16x8_t v; uint32 u[4]; } t_;                          \
  t_.u[0] = cvtpk_bf16(xf[(base)+0]*(h), xf[(base)+1]*(h));       \
  t_.u[1] = cvtpk_bf16(xf[(base)+2]*(h), xf[(base)+3]*(h));       \
  t_.u[2] = cvtpk_bf16(xf[(base)+4]*(h), xf[(base)+5]*(h));       \
  t_.u[3] = cvtpk_bf16(xf[(base)+6]*(h), xf[(base)+7]*(h));       \
  dst = t_.v; }

__global__ __launch_bounds__(256) void kv_kernel(
    const ushort_t* __restrict__ W3bf,
    const float* __restrict__ h2_ws, const float* __restrict__ xe_ws,
    float* __restrict__ kv_ws) {
  int bx = blockIdx.x;
  int eb = bx >> 2, ob = bx & 3;       // 128 edge-groups x 4 col-groups
  int o0 = ob * 64;
  int tid = threadIdx.x;
  int we = tid >> 6, l = tid & 63;
  int l15 = l & 15, g = l >> 4;        // g in 0..3
  int ebase = eb * 64;
  __shared__ float h2_s[64 * 68];                  // 17408 B
  __shared__ ushort_t bstage[2][2][4096];          // 2 bufs x 2 rows x 8KB = 32768 B
  {  // stage h2 tile [64 edges][64 r], stride 68
    int row = tid >> 2, c0 = (tid & 3) * 16;
    const float* src = h2_ws + (ebase + row) * RH + c0;
    float* dst = &h2_s[row * 68 + c0];
    #pragma unroll
    for (int q = 0; q < 4; ++q) ((float4*)dst)[q] = ((const float4*)src)[q];
  }
  // xe fragment (fp32) from global: one edge row per lane (M=16 per wave)
  int erow = ebase + we * 16 + l15;
  const float* xsrc = xe_ws + erow * DD + g * 8;
  float xf[16];
  #pragma unroll
  for (int jj = 0; jj < 8; ++jj) { xf[jj] = xsrc[jj]; xf[8 + jj] = xsrc[32 + jj]; }

  // B staging: rows {r0, r0+1} (clamped to 64) -> bstage[buf][0/1], linear copy
  #define STAGE(buf, r0_) {                                                   \
    int ra_ = ((r0_) > 64) ? 64 : (r0_);                                      \
    int rb_ = ((r0_) + 1 > 64) ? 64 : ((r0_) + 1);                            \
    const ushort_t* sa_ = W3bf + ((size_t)ra_ << 14) + o0 * 64;               \
    const ushort_t* sb_ = W3bf + ((size_t)rb_ << 14) + o0 * 64;               \
    ushort_t* da_ = &bstage[buf][0][0];                                       \
    ushort_t* db_ = &bstage[buf][1][0];                                       \
    __builtin_amdgcn_global_load_lds((glb_us*)(sa_ + tid * 8),        (lds_us*)(da_ + tid * 8), 16, 0, 0);        \
    __builtin_amdgcn_global_load_lds((glb_us*)(sa_ + 2048 + tid * 8), (lds_us*)(da_ + 2048 + tid * 8), 16, 0, 0); \
    __builtin_amdgcn_global_load_lds((glb_us*)(sb_ + tid * 8),        (lds_us*)(db_ + tid * 8), 16, 0, 0);        \
    __builtin_amdgcn_global_load_lds((glb_us*)(sb_ + 2048 + tid * 8), (lds_us*)(db_ + 2048 + tid * 8), 16, 0, 0); }

  STAGE(0, 0);
  asm volatile("s_waitcnt vmcnt(0)" ::: "memory");
  __syncthreads();

  int e68 = (we * 16 + l15) * 68;
  int swz = (l15 & 7) << 4;
  f32x4_t acc0 = {0,0,0,0}, acc1 = {0,0,0,0}, acc2 = {0,0,0,0}, acc3 = {0,0,0,0};
  int cur = 0;
  for (int p = 0; p < 33; ++p) {
    int r0 = 2 * p;
    if (p < 32) STAGE(cur ^ 1, r0 + 2);
    #pragma unroll
    for (int rl = 0; rl < 2; ++rl) {
      int r = r0 + rl;
      if (r > 64) break;                      // phase 32 has only row 64
      const char* bp = (const char*)&bstage[cur][rl][0];
      // swizzled frag reads: o_local = l15 + oi*16; k-halves gr = g and 4+g
      bf16x8_t bf0 = *(const bf16x8_t*)(bp + l15*128 +    0 + ((g*16)     ^ swz));
      bf16x8_t bf1 = *(const bf16x8_t*)(bp + l15*128 +    0 + (((4+g)*16) ^ swz));
      bf16x8_t bf2 = *(const bf16x8_t*)(bp + l15*128 + 2048 + ((g*16)     ^ swz));
      bf16x8_t bf3 = *(const bf16x8_t*)(bp + l15*128 + 2048 + (((4+g)*16) ^ swz));
      bf16x8_t bf4 = *(const bf16x8_t*)(bp + l15*128 + 4096 + ((g*16)     ^ swz));
      bf16x8_t bf5 = *(const bf16x8_t*)(bp + l15*128 + 4096 + (((4+g)*16) ^ swz));
      bf16x8_t bf6 = *(const bf16x8_t*)(bp + l15*128 + 6144 + ((g*16)     ^ swz));
      bf16x8_t bf7 = *(const bf16x8_t*)(bp + l15*128 + 6144 + (((4+g)*16) ^ swz));
      float h = (r < 64) ? h2_s[e68 + r] : 1.0f;
      bf16x8_t a0, a1;
      AFRAG(a0, 0, h); AFRAG(a1, 8, h);
      acc0 = __builtin_amdgcn_mfma_f32_16x16x32_bf16(a0, bf0, acc0, 0, 0, 0);
      acc0 = __builtin_amdgcn_mfma_f32_16x16x32_bf16(a1, bf1, acc0, 0, 0, 0);
      acc1 = __builtin_amdgcn_mfma_f32_16x16x32_bf16(a0, bf2, acc1, 0, 0, 0);
      acc1 = __builtin_amdgcn_mfma_f32_16x16x32_bf16(a1, bf3, acc1, 0, 0, 0);
      acc2 = __builtin_amdgcn_mfma_f32_16x16x32_bf16(a0, bf4, acc2, 0, 0, 0);
      acc2 = __builtin_amdgcn_mfma_f32_16x16x32_bf16(a1, bf5, acc2, 0, 0, 0);
      acc3 = __builtin_amdgcn_mfma_f32_16x16x32_bf16(a0, bf6, acc3, 0, 0, 0);
      acc3 = __builtin_amdgcn_mfma_f32_16x16x32_bf16(a1, bf7, acc3, 0, 0, 0);
    }
    asm volatile("s_waitcnt vmcnt(0)" ::: "memory");
    __syncthreads();
    cur ^= 1;
  }
  // D layout (m89-verified): col = lane&15, row = (lane>>4)*4 + reg
  int orow = (ebase + we * 16 + g * 4) * KVD + o0 + l15;
  #pragma unroll
  for (int q = 0; q < 4; ++q) {
    kv_ws[orow + q * KVD +  0] = acc0[q];
    kv_ws[orow + q * KVD + 16] = acc1[q];
    kv_ws[orow + q * KVD + 32] = acc2[q];
    kv_ws[orow + q * KVD + 48] = acc3[q];
  }
}

// ---------------- Kernel 4: fused (kv @ Wkv_out) + L2-dist attention + out-proj ---
__global__ __launch_bounds__(128) void attn_kernel(
    const float* __restrict__ q_ws, const float* __restrict__ kv_ws,
    const int* __restrict__ maskp, const float* __restrict__ Wkv,
    const float* __restrict__ Wout, float* __restrict__ out) {
  int node = blockIdx.x;
  int t = threadIdx.x;             // 128 = H*dh
  int h = t >> 5;
  __shared__ float kvs[KK * 260];
  __shared__ float sim_s[NH * KK];
  __shared__ float o_s[HID];
  {
    int e = t >> 3, c0 = (t & 7) * 32;
    const float* src = kv_ws + (node * KK + e) * KVD + c0;
    float* dst = &kvs[e * 260 + c0];
    #pragma unroll
    for (int q = 0; q < 8; ++q) ((float4*)dst)[q] = ((const float4*)src)[q];
  }
  __syncthreads();
  float kk2[KK] = {}, vv2[KK] = {};
  #pragma unroll 4
  for (int k = 0; k < KVD; ++k) {
    float w1 = Wkv[k * KVD + t];
    float w2 = Wkv[k * KVD + 128 + t];
    #pragma unroll
    for (int e = 0; e < KK; ++e) {
      float kvv = kvs[e * 260 + k];
      kk2[e] += kvv * w1;
      vv2[e] += kvv * w2;
    }
  }
  float qv = q_ws[node * HID + t];
  const float scale = 0.17677669529663689f;   // 32^-0.5
  #pragma unroll
  for (int j = 0; j < KK; ++j) {
    float diff = qv - kk2[j] + 1e-6f;
    float s = grp32_sum(diff * diff);
    if ((t & 31) == 0) sim_s[h * KK + j] = -sqrtf(s) * scale;
  }
  __syncthreads();
  float sv[KK];
  float m = -FLT_MAX;
  #pragma unroll
  for (int j = 0; j < KK; ++j) {
    bool msk = maskp[node * KK + j] != 0;
    float s = msk ? sim_s[h * KK + j] : -FLT_MAX;
    sv[j] = s;
    m = fmaxf(m, s);
  }
  float sum = 0.f, wv[KK];
  #pragma unroll
  for (int j = 0; j < KK; ++j) { wv[j] = expf(sv[j] - m); sum += wv[j]; }
  float inv = 1.f / sum;
  float ot = 0.f;
  #pragma unroll
  for (int j = 0; j < KK; ++j) ot += wv[j] * vv2[j];
  o_s[t] = ot * inv;
  __syncthreads();
  if (t < DD) {
    float r = 0.f;
    #pragma unroll 4
    for (int cI = 0; cI < HID; ++cI) r += o_s[cI] * Wout[cI * DD + t];
    out[node * DD + t] = r;
  }
}

extern "C" void kernel_launch(void* const* d_in, const int* in_sizes, int n_in,
                              void* d_out, int out_size, void* d_ws, size_t ws_size,
                              hipStream_t stream) {
  const float* feat = (const float*)d_in[0];
  const int*   nbi  = (const int*)d_in[1];
  const int*   msk  = (const int*)d_in[2];
  const float* rel  = (const float*)d_in[3];
  const float* gsc  = (const float*)d_in[4];
  const float* Wq   = (const float*)d_in[5];
  const float* Wxi  = (const float*)d_in[6];
  const float* Wxj  = (const float*)d_in[7];
  const float* W1   = (const float*)d_in[8];
  const float* b1   = (const float*)d_in[9];
  const float* g1   = (const float*)d_in[10];
  const float* W2   = (const float*)d_in[11];
  const float* b2   = (const float*)d_in[12];
  const float* g2   = (const float*)d_in[13];
  const float* W3   = (const float*)d_in[14];
  const float* b3   = (const float*)d_in[15];
  const float* Wkv  = (const float*)d_in[16];
  const float* Wout = (const float*)d_in[17];

  float* ws      = (float*)d_ws;
  float* q_ws    = ws;                          // 512*128
  float* xi_ws   = q_ws  + NNODES * HID;        // 512*64
  float* xj_ws   = xi_ws + NNODES * DD;         // 512*64
  float* h2_ws   = xj_ws + NNODES * DD;         // 8192*64
  float* xe_ws   = h2_ws + NEDGES * RH;         // 8192*64
  float* kv_ws   = xe_ws + NEDGES * DD;         // 8192*256
  ushort_t* W3bf = (ushort_t*)(kv_ws + NEDGES * KVD);   // 65*16384 bf16 (~2.1 MB)

  node_w3_kernel<<<648, 256, 0, stream>>>(feat, gsc, Wq, Wxi, Wxj, W3, b3,
                                          q_ws, xi_ws, xj_ws, W3bf);
  edge_kernel<<<NEDGES, 64, 0, stream>>>(nbi, rel, W1, b1, g1, W2, b2, g2,
                                         xi_ws, xj_ws, h2_ws, xe_ws);
  kv_kernel<<<512, 256, 0, stream>>>(W3bf, h2_ws, xe_ws, kv_ws);
  attn_kernel<<<NNODES, 128, 0, stream>>>(q_ws, kv_ws, msk, Wkv, Wout,
                                          (float*)d_out);
}

// Round 11
// 164.182 us; speedup vs baseline: 1.3429x; 1.1316x over previous
//
#include <hip/hip_runtime.h>
#include <hip/hip_bf16.h>
#include <float.h>

#define BB 2
#define NN 256
#define DD 64
#define KK 16
#define NH 4
#define HID 128
#define KVD 256
#define RH 64
#define NNODES (BB*NN)      // 512
#define NEDGES (NNODES*KK)  // 8192

typedef unsigned int uint32;
typedef unsigned short ushort_t;
typedef float f32x4_t __attribute__((ext_vector_type(4)));
typedef short bf16x8_t __attribute__((ext_vector_type(8)));
typedef __attribute__((address_space(3))) ushort_t lds_us;
typedef __attribute__((address_space(1))) const ushort_t glb_us;

__device__ __forceinline__ uint32 cvtpk_bf16(float lo, float hi) {
  uint32 r;
  asm("v_cvt_pk_bf16_f32 %0, %1, %2" : "=v"(r) : "v"(lo), "v"(hi));
  return r;
}

__device__ __forceinline__ float wave_sum64(float v) {
  #pragma unroll
  for (int m = 32; m; m >>= 1) v += __shfl_xor(v, m, 64);
  return v;
}

__device__ __forceinline__ ushort_t rne_bf16(float f) {
  uint32 u = __float_as_uint(f);
  return (ushort_t)((u + 0x7FFFu + ((u >> 16) & 1u)) >> 16);
}

// ---------------- Kernel 1: [0..127] prenorm+q/xi/xj | [128..647] W3->bf16 swizzled
//                  [648..711] Wkv -> bf16 TRANSPOSED [n][k] ------------------------
__global__ __launch_bounds__(256) void node_w3_kernel(
    const float* __restrict__ feat, const float* __restrict__ gscale,
    const float* __restrict__ Wq, const float* __restrict__ Wxi,
    const float* __restrict__ Wxj,
    const float* __restrict__ W3, const float* __restrict__ b3,
    const float* __restrict__ Wkv,
    float* __restrict__ q_ws, float* __restrict__ xi_ws, float* __restrict__ xj_ws,
    ushort_t* __restrict__ W3bf, ushort_t* __restrict__ Wkvt) {
  int bx = blockIdx.x;
  if (bx >= 648) {
    // ---- Wkv transpose+convert: Wkvt[n*256+k] = bf16(Wkv[k*256+n])
    int i = ((bx - 648) * 256 + threadIdx.x) * 4;   // 64 blocks cover 65536 elems
    int n = i >> 8, k0 = i & 255;
    union { uint2 q; ushort_t s[4]; } o;
    #pragma unroll
    for (int j = 0; j < 4; ++j) o.s[j] = rne_bf16(Wkv[(k0 + j) * KVD + n]);
    *(uint2*)(Wkvt + n * KVD + k0) = o.q;
    return;
  }
  if (bx >= 128) {
    // ---- W3 convert, swizzled layout: byte (o,d): o*128 + ((gr*16)^((o&7)<<4))
    const int W3N = 64 * KVD * DD;               // 1,048,576
    int i = ((bx - 128) * 256 + threadIdx.x) * 8;
    const float* src = (i < W3N) ? (W3 + i) : (b3 + (i - W3N));
    float4 a = ((const float4*)src)[0];
    float4 b = ((const float4*)src)[1];
    float v[8] = {a.x, a.y, a.z, a.w, b.x, b.y, b.z, b.w};
    union { uint4 q; ushort_t s[8]; } o;
    #pragma unroll
    for (int jj = 0; jj < 8; ++jj) o.s[jj] = rne_bf16(v[jj]);
    int rr = i >> 14, j0 = i & 16383;
    int oc = j0 >> 6, gr = (j0 >> 3) & 7;
    int byte_sw = oc * 128 + ((gr * 16) ^ ((oc & 7) << 4));
    *(uint4*)(W3bf + (rr << 14) + (byte_sw >> 1)) = o.q;
    return;
  }
  int sub = threadIdx.x >> 6;
  int t = threadIdx.x & 63;
  int node = bx * 4 + sub;
  __shared__ float xs[4][DD];
  float f = feat[node * DD + t];
  float ss = wave_sum64(f * f);
  float rms = sqrtf(ss) * 0.125f;
  float den = fmaxf(rms, 1e-12f);
  float x = f / den * gscale[t];
  xs[sub][t] = x;
  __syncthreads();
  float q0 = 0.f, q1 = 0.f, xiv = 0.f, xjv = 0.f;
  #pragma unroll 4
  for (int d = 0; d < DD; ++d) {
    float xv = xs[sub][d];
    q0  += xv * Wq[d * HID + t];
    q1  += xv * Wq[d * HID + 64 + t];
    xiv += xv * Wxi[d * DD + t];
    xjv += xv * Wxj[d * DD + t];
  }
  q_ws[node * HID + t] = q0;
  q_ws[node * HID + 64 + t] = q1;
  xi_ws[node * DD + t] = xiv;
  xj_ws[node * DD + t] = xjv;
}

// ---------------- Kernel 2: radial MLP (2 LN layers) + xe gather (one block per edge)
__global__ __launch_bounds__(64) void edge_kernel(
    const int* __restrict__ nbi, const float* __restrict__ rel,
    const float* __restrict__ W1, const float* __restrict__ b1,
    const float* __restrict__ g1, const float* __restrict__ W2,
    const float* __restrict__ b2, const float* __restrict__ g2,
    const float* __restrict__ xi_ws, const float* __restrict__ xj_ws,
    float* __restrict__ h2_ws, float* __restrict__ xe_ws) {
  int e = blockIdx.x;
  int t = threadIdx.x;
  int node = e >> 4;
  int j = e & 15;
  int bb = node >> 8;
  __shared__ float hs[RH];
  float rd = rel[e];
  float h = rd * W1[t] + b1[t];
  h = h / (1.f + expf(-h));                          // silu
  float mu = wave_sum64(h) * (1.f / RH);
  float c = h - mu;
  float var = wave_sum64(c * c) * (1.f / RH);
  float xn = c * rsqrtf(var + 1e-5f) * g1[t];
  hs[t] = xn;
  __syncthreads();
  float p = b2[t];
  #pragma unroll 4
  for (int r = 0; r < RH; ++r) p += hs[r] * W2[r * RH + t];
  p = p / (1.f + expf(-p));
  mu = wave_sum64(p) * (1.f / RH);
  c = p - mu;
  var = wave_sum64(c * c) * (1.f / RH);
  float h2v = c * rsqrtf(var + 1e-5f) * g2[t];
  h2_ws[e * RH + t] = h2v;
  int nb = nbi[node * KK + j];
  xe_ws[e * DD + t] = xj_ws[(bb * NN + nb) * DD + t] + xi_ws[node * DD + t];
}

// ---------------- Kernel 3: kv via bf16 MFMA, LDS-staged B (global_load_lds) ------
#define AFRAG(dst, base, h) {                                     \
  union { bf16x8_t v; uint32 u[4]; } t_;                          \
  t_.u[0] = cvtpk_bf16(xf[(base)+0]*(h), xf[(base)+1]*(h));       \
  t_.u[1] = cvtpk_bf16(xf[(base)+2]*(h), xf[(base)+3]*(h));       \
  t_.u[2] = cvtpk_bf16(xf[(base)+4]*(h), xf[(base)+5]*(h));       \
  t_.u[3] = cvtpk_bf16(xf[(base)+6]*(h), xf[(base)+7]*(h));       \
  dst = t_.v; }

__global__ __launch_bounds__(256) void kv_kernel(
    const ushort_t* __restrict__ W3bf,
    const float* __restrict__ h2_ws, const float* __restrict__ xe_ws,
    float* __restrict__ kv_ws) {
  int bx = blockIdx.x;
  int eb = bx >> 2, ob = bx & 3;       // 128 edge-groups x 4 col-groups
  int o0 = ob * 64;
  int tid = threadIdx.x;
  int we = tid >> 6, l = tid & 63;
  int l15 = l & 15, g = l >> 4;        // g in 0..3
  int ebase = eb * 64;
  __shared__ float h2_s[64 * 68];                  // 17408 B
  __shared__ ushort_t bstage[2][2][4096];          // 32768 B
  {
    int row = tid >> 2, c0 = (tid & 3) * 16;
    const float* src = h2_ws + (ebase + row) * RH + c0;
    float* dst = &h2_s[row * 68 + c0];
    #pragma unroll
    for (int q = 0; q < 4; ++q) ((float4*)dst)[q] = ((const float4*)src)[q];
  }
  int erow = ebase + we * 16 + l15;
  const float* xsrc = xe_ws + erow * DD + g * 8;
  float xf[16];
  #pragma unroll
  for (int jj = 0; jj < 8; ++jj) { xf[jj] = xsrc[jj]; xf[8 + jj] = xsrc[32 + jj]; }

  #define STAGE(buf, r0_) {                                                   \
    int ra_ = ((r0_) > 64) ? 64 : (r0_);                                      \
    int rb_ = ((r0_) + 1 > 64) ? 64 : ((r0_) + 1);                            \
    const ushort_t* sa_ = W3bf + ((size_t)ra_ << 14) + o0 * 64;               \
    const ushort_t* sb_ = W3bf + ((size_t)rb_ << 14) + o0 * 64;               \
    ushort_t* da_ = &bstage[buf][0][0];                                       \
    ushort_t* db_ = &bstage[buf][1][0];                                       \
    __builtin_amdgcn_global_load_lds((glb_us*)(sa_ + tid * 8),        (lds_us*)(da_ + tid * 8), 16, 0, 0);        \
    __builtin_amdgcn_global_load_lds((glb_us*)(sa_ + 2048 + tid * 8), (lds_us*)(da_ + 2048 + tid * 8), 16, 0, 0); \
    __builtin_amdgcn_global_load_lds((glb_us*)(sb_ + tid * 8),        (lds_us*)(db_ + tid * 8), 16, 0, 0);        \
    __builtin_amdgcn_global_load_lds((glb_us*)(sb_ + 2048 + tid * 8), (lds_us*)(db_ + 2048 + tid * 8), 16, 0, 0); }

  STAGE(0, 0);
  asm volatile("s_waitcnt vmcnt(0)" ::: "memory");
  __syncthreads();

  int e68 = (we * 16 + l15) * 68;
  int swz = (l15 & 7) << 4;
  f32x4_t acc0 = {0,0,0,0}, acc1 = {0,0,0,0}, acc2 = {0,0,0,0}, acc3 = {0,0,0,0};
  int cur = 0;
  for (int p = 0; p < 33; ++p) {
    int r0 = 2 * p;
    if (p < 32) STAGE(cur ^ 1, r0 + 2);
    #pragma unroll
    for (int rl = 0; rl < 2; ++rl) {
      int r = r0 + rl;
      if (r > 64) break;
      const char* bp = (const char*)&bstage[cur][rl][0];
      bf16x8_t bf0 = *(const bf16x8_t*)(bp + l15*128 +    0 + ((g*16)     ^ swz));
      bf16x8_t bf1 = *(const bf16x8_t*)(bp + l15*128 +    0 + (((4+g)*16) ^ swz));
      bf16x8_t bf2 = *(const bf16x8_t*)(bp + l15*128 + 2048 + ((g*16)     ^ swz));
      bf16x8_t bf3 = *(const bf16x8_t*)(bp + l15*128 + 2048 + (((4+g)*16) ^ swz));
      bf16x8_t bf4 = *(const bf16x8_t*)(bp + l15*128 + 4096 + ((g*16)     ^ swz));
      bf16x8_t bf5 = *(const bf16x8_t*)(bp + l15*128 + 4096 + (((4+g)*16) ^ swz));
      bf16x8_t bf6 = *(const bf16x8_t*)(bp + l15*128 + 6144 + ((g*16)     ^ swz));
      bf16x8_t bf7 = *(const bf16x8_t*)(bp + l15*128 + 6144 + (((4+g)*16) ^ swz));
      float h = (r < 64) ? h2_s[e68 + r] : 1.0f;
      bf16x8_t a0, a1;
      AFRAG(a0, 0, h); AFRAG(a1, 8, h);
      acc0 = __builtin_amdgcn_mfma_f32_16x16x32_bf16(a0, bf0, acc0, 0, 0, 0);
      acc0 = __builtin_amdgcn_mfma_f32_16x16x32_bf16(a1, bf1, acc0, 0, 0, 0);
      acc1 = __builtin_amdgcn_mfma_f32_16x16x32_bf16(a0, bf2, acc1, 0, 0, 0);
      acc1 = __builtin_amdgcn_mfma_f32_16x16x32_bf16(a1, bf3, acc1, 0, 0, 0);
      acc2 = __builtin_amdgcn_mfma_f32_16x16x32_bf16(a0, bf4, acc2, 0, 0, 0);
      acc2 = __builtin_amdgcn_mfma_f32_16x16x32_bf16(a1, bf5, acc2, 0, 0, 0);
      acc3 = __builtin_amdgcn_mfma_f32_16x16x32_bf16(a0, bf6, acc3, 0, 0, 0);
      acc3 = __builtin_amdgcn_mfma_f32_16x16x32_bf16(a1, bf7, acc3, 0, 0, 0);
    }
    asm volatile("s_waitcnt vmcnt(0)" ::: "memory");
    __syncthreads();
    cur ^= 1;
  }
  int orow = (ebase + we * 16 + g * 4) * KVD + o0 + l15;
  #pragma unroll
  for (int q = 0; q < 4; ++q) {
    kv_ws[orow + q * KVD +  0] = acc0[q];
    kv_ws[orow + q * KVD + 16] = acc1[q];
    kv_ws[orow + q * KVD + 32] = acc2[q];
    kv_ws[orow + q * KVD + 48] = acc3[q];
  }
}

// ---------------- Kernel 4: MFMA (kv @ Wkv_t) + L2-dist attention + out-proj ------
// Block = 1 node, 128 thr = 2 waves. Wave w: output cols [w*128, +128) (w0=K, w1=V).
// Fragment recipe (verified in kv_kernel): A lane(g,l15): row l15, k=c*32+g*8+j;
//   B lane: col l15, same k;  D lane reg q: row g*4+q, col l15.
__global__ __launch_bounds__(128) void attn_kernel(
    const float* __restrict__ q_ws, const float* __restrict__ kv_ws,
    const int* __restrict__ maskp, const ushort_t* __restrict__ Wkvt,
    const float* __restrict__ Wout, float* __restrict__ out) {
  int node = blockIdx.x;
  int tid = threadIdx.x;
  int w = tid >> 6, l = tid & 63;
  int l15 = l & 15, g = l >> 4;
  __shared__ float attn_s[NH * KK];
  __shared__ float o_s[HID];
  // A fragments: kv row l15 (fp32 -> bf16), 8 k-chunks
  bf16x8_t a[8];
  {
    const float* kvrow = kv_ws + (size_t)(node * KK + l15) * KVD + g * 8;
    #pragma unroll
    for (int c = 0; c < 8; ++c) {
      union { bf16x8_t v; uint32 u[4]; } t_;
      t_.u[0] = cvtpk_bf16(kvrow[c*32 + 0], kvrow[c*32 + 1]);
      t_.u[1] = cvtpk_bf16(kvrow[c*32 + 2], kvrow[c*32 + 3]);
      t_.u[2] = cvtpk_bf16(kvrow[c*32 + 4], kvrow[c*32 + 5]);
      t_.u[3] = cvtpk_bf16(kvrow[c*32 + 6], kvrow[c*32 + 7]);
      a[c] = t_.v;
    }
  }
  // MFMA: 8 n-tiles x 8 k-chunks
  f32x4_t acc[8];
  #pragma unroll
  for (int nt = 0; nt < 8; ++nt) {
    acc[nt] = (f32x4_t){0.f, 0.f, 0.f, 0.f};
    const ushort_t* bbase = Wkvt + (size_t)(w * 128 + nt * 16 + l15) * KVD + g * 8;
    #pragma unroll
    for (int c = 0; c < 8; ++c) {
      bf16x8_t b = *(const bf16x8_t*)(bbase + c * 32);
      acc[nt] = __builtin_amdgcn_mfma_f32_16x16x32_bf16(a[c], b, acc[nt], 0, 0, 0);
    }
  }
  const float scale = 0.17677669529663689f;   // 32^-0.5
  if (w == 0) {
    // acc[nt][q] = kk2[edge g*4+q][col nt*16+l15]; head h = nt>>1
    float sim[4][4];   // [q][h]
    #pragma unroll
    for (int h = 0; h < 4; ++h) {
      #pragma unroll
      for (int q = 0; q < 4; ++q) {
        float s = 0.f;
        #pragma unroll
        for (int p = 0; p < 2; ++p) {
          int nt = h * 2 + p;
          float qv = q_ws[node * HID + nt * 16 + l15];
          float diff = qv - acc[nt][q] + 1e-6f;
          s += diff * diff;
        }
        #pragma unroll
        for (int m = 8; m; m >>= 1) s += __shfl_xor(s, m, 64);  // over l15 group
        sim[q][h] = -sqrtf(s) * scale;
      }
    }
    int mv[4];
    #pragma unroll
    for (int q = 0; q < 4; ++q) mv[q] = maskp[node * KK + g * 4 + q];
    #pragma unroll
    for (int h = 0; h < 4; ++h) {
      float sv[4];
      float mx = -FLT_MAX;
      #pragma unroll
      for (int q = 0; q < 4; ++q) {
        sv[q] = mv[q] ? sim[q][h] : -FLT_MAX;
        mx = fmaxf(mx, sv[q]);
      }
      mx = fmaxf(mx, __shfl_xor(mx, 16, 64));   // across g
      mx = fmaxf(mx, __shfl_xor(mx, 32, 64));
      float se = 0.f, ev[4];
      #pragma unroll
      for (int q = 0; q < 4; ++q) { ev[q] = expf(sv[q] - mx); se += ev[q]; }
      se += __shfl_xor(se, 16, 64);
      se += __shfl_xor(se, 32, 64);
      float inv = 1.f / se;
      if (l15 == 0) {
        #pragma unroll
        for (int q = 0; q < 4; ++q) attn_s[h * KK + g * 4 + q] = ev[q] * inv;
      }
    }
  }
  __syncthreads();
  if (w == 1) {
    // acc[nt][q] = vv2[edge g*4+q][vcol nt*16+l15]; head = nt>>1
    #pragma unroll
    for (int nt = 0; nt < 8; ++nt) {
      int h = nt >> 1;
      float o = 0.f;
      #pragma unroll
      for (int q = 0; q < 4; ++q) o += attn_s[h * KK + g * 4 + q] * acc[nt][q];
      o += __shfl_xor(o, 16, 64);   // across g
      o += __shfl_xor(o, 32, 64);
      if (g == 0) o_s[nt * 16 + l15] = o;
    }
  }
  __syncthreads();
  if (tid < DD) {
    float r = 0.f;
    #pragma unroll 4
    for (int cI = 0; cI < HID; ++cI) r += o_s[cI] * Wout[cI * DD + tid];
    out[node * DD + tid] = r;
  }
}

extern "C" void kernel_launch(void* const* d_in, const int* in_sizes, int n_in,
                              void* d_out, int out_size, void* d_ws, size_t ws_size,
                              hipStream_t stream) {
  const float* feat = (const float*)d_in[0];
  const int*   nbi  = (const int*)d_in[1];
  const int*   msk  = (const int*)d_in[2];
  const float* rel  = (const float*)d_in[3];
  const float* gsc  = (const float*)d_in[4];
  const float* Wq   = (const float*)d_in[5];
  const float* Wxi  = (const float*)d_in[6];
  const float* Wxj  = (const float*)d_in[7];
  const float* W1   = (const float*)d_in[8];
  const float* b1   = (const float*)d_in[9];
  const float* g1   = (const float*)d_in[10];
  const float* W2   = (const float*)d_in[11];
  const float* b2   = (const float*)d_in[12];
  const float* g2   = (const float*)d_in[13];
  const float* W3   = (const float*)d_in[14];
  const float* b3   = (const float*)d_in[15];
  const float* Wkv  = (const float*)d_in[16];
  const float* Wout = (const float*)d_in[17];

  float* ws      = (float*)d_ws;
  float* q_ws    = ws;                          // 512*128
  float* xi_ws   = q_ws  + NNODES * HID;        // 512*64
  float* xj_ws   = xi_ws + NNODES * DD;         // 512*64
  float* h2_ws   = xj_ws + NNODES * DD;         // 8192*64
  float* xe_ws   = h2_ws + NEDGES * RH;         // 8192*64
  float* kv_ws   = xe_ws + NEDGES * DD;         // 8192*256
  ushort_t* W3bf = (ushort_t*)(kv_ws + NEDGES * KVD);   // 65*16384 bf16 (~2.1 MB)
  ushort_t* Wkvt = W3bf + 65 * 16384;                   // 256*256 bf16 (128 KB)

  node_w3_kernel<<<712, 256, 0, stream>>>(feat, gsc, Wq, Wxi, Wxj, W3, b3, Wkv,
                                          q_ws, xi_ws, xj_ws, W3bf, Wkvt);
  edge_kernel<<<NEDGES, 64, 0, stream>>>(nbi, rel, W1, b1, g1, W2, b2, g2,
                                         xi_ws, xj_ws, h2_ws, xe_ws);
  kv_kernel<<<512, 256, 0, stream>>>(W3bf, h2_ws, xe_ws, kv_ws);
  attn_kernel<<<NNODES, 128, 0, stream>>>(q_ws, kv_ws, msk, Wkvt, Wout,
                                          (float*)d_out);
}